// Round 1
// baseline (364.271 us; speedup 1.0000x reference)
//
#include <hip/hip_runtime.h>
#include <hip/hip_bf16.h>

typedef unsigned int u32;
typedef unsigned short u16;
typedef __attribute__((ext_vector_type(4))) float f32x4;
typedef __attribute__((ext_vector_type(8))) short bf16x8;

#define N_NODES 100000
#define N_EDGES 50000
#define D0      128
#define DEG_E   16
#define DEG_N   8
#define MPAD    100096
#define DF      512
#define HIDN    256
#define NC      40
#define NCP     48

__device__ __forceinline__ float b2f(u32 h) { return __uint_as_float(h << 16); }
__device__ __forceinline__ u16 f2b(float f) {
  u32 u = __float_as_uint(f);
  u32 r = (u + 0x7fffu + ((u >> 16) & 1u)) >> 16;
  return (u16)r;
}
__device__ __forceinline__ void load_lds16(const void* g, void* l) {
  __builtin_amdgcn_global_load_lds((const __attribute__((address_space(1))) u32*)g,
                                   (__attribute__((address_space(3))) u32*)l, 16, 0, 0);
}

// ---- prep kernels -------------------------------------------------------

// node_x f32 (100000x128) -> X3[:, 0:128] bf16 (row stride 512)
__global__ __launch_bounds__(256) void k_node_to_x3(const float* __restrict__ x, u16* __restrict__ X3) {
  int t = blockIdx.x * 256 + threadIdx.x;           // 3.2M threads, 4 elems each
  int e4 = t * 4;
  int row = e4 >> 7, col = e4 & 127;
  const float4 v = *(const float4*)(x + e4);
  ushort4 o;
  o.x = f2b(v.x); o.y = f2b(v.y); o.z = f2b(v.z); o.w = f2b(v.w);
  *(ushort4*)(X3 + (size_t)row * DF + col) = o;
}

// zero the 96 pad rows of X3 (full 512 cols, contiguous region)
__global__ __launch_bounds__(256) void k_zero_pad(u16* __restrict__ X3) {
  int t = blockIdx.x * 256 + threadIdx.x;           // 12288 threads * 4 elems
  ushort4 z; z.x = z.y = z.z = z.w = 0;
  *(ushort4*)(X3 + (size_t)N_NODES * DF + t * 4) = z;
}

// W1 (512x256 f32, K-major) -> W1T (256x512 bf16, N-major)
__global__ __launch_bounds__(256) void k_w1t(const float* __restrict__ W1, u16* __restrict__ W1T) {
  int t = blockIdx.x * 256 + threadIdx.x;           // 131072
  int k = t >> 8, n = t & 255;
  W1T[(size_t)n * DF + k] = f2b(W1[t]);
}

// W2 (256x40 f32) -> W2T (48x256 bf16, N-major, rows 40..47 zero)
__global__ __launch_bounds__(256) void k_w2t(const float* __restrict__ W2, u16* __restrict__ W2T) {
  int t = blockIdx.x * 256 + threadIdx.x;           // 48*256
  int n = t >> 8, k = t & 255;
  W2T[t] = (n < NC) ? f2b(W2[k * NC + n]) : (u16)0;
}

// ---- gather / segment-mean kernels (wave per segment) -------------------

// layer1 N2E: mean of 16 gathered X3[:,0:128] rows -> E1 (50000x128)
__global__ __launch_bounds__(256) void k_n2e1(const u16* __restrict__ X3, const int* __restrict__ nmap,
                                              u16* __restrict__ E1) {
  int gw = (blockIdx.x * 256 + threadIdx.x) >> 6;   // edge id
  int lane = threadIdx.x & 63;
  int my = (lane < DEG_E) ? nmap[gw * DEG_E + lane] : 0;
  float a0 = 0.f, a1 = 0.f;
#pragma unroll
  for (int r = 0; r < DEG_E; ++r) {
    int idx = __shfl(my, r);
    u32 v = *(const u32*)(X3 + (size_t)idx * DF + lane * 2);
    a0 += b2f(v & 0xffffu); a1 += b2f(v >> 16);
  }
  const float s = 1.f / DEG_E;
  u32 o = (u32)f2b(fmaxf(a0 * s, 0.f)) | ((u32)f2b(fmaxf(a1 * s, 0.f)) << 16);
  *(u32*)(E1 + (size_t)gw * D0 + lane * 2) = o;
}

// layer1 E2N: mean of 8 gathered E1 rows -> X3[:, 128:256]
__global__ __launch_bounds__(256) void k_e2n1(const u16* __restrict__ E1, const int* __restrict__ emap,
                                              u16* __restrict__ X3) {
  int gw = (blockIdx.x * 256 + threadIdx.x) >> 6;   // node id
  int lane = threadIdx.x & 63;
  int my = (lane < DEG_N) ? emap[gw * DEG_N + lane] : 0;
  float a0 = 0.f, a1 = 0.f;
#pragma unroll
  for (int r = 0; r < DEG_N; ++r) {
    int idx = __shfl(my, r);
    u32 v = *(const u32*)(E1 + (size_t)idx * D0 + lane * 2);
    a0 += b2f(v & 0xffffu); a1 += b2f(v >> 16);
  }
  const float s = 1.f / DEG_N;
  u32 o = (u32)f2b(fmaxf(a0 * s, 0.f)) | ((u32)f2b(fmaxf(a1 * s, 0.f)) << 16);
  *(u32*)(X3 + (size_t)gw * DF + D0 + lane * 2) = o;
}

// layer2 N2E: mean of 16 gathered X3[:,0:256] rows -> E2 (50000x256)
__global__ __launch_bounds__(256) void k_n2e2(const u16* __restrict__ X3, const int* __restrict__ nmap,
                                              u16* __restrict__ E2) {
  int gw = (blockIdx.x * 256 + threadIdx.x) >> 6;
  int lane = threadIdx.x & 63;
  int my = (lane < DEG_E) ? nmap[gw * DEG_E + lane] : 0;
  float a0 = 0.f, a1 = 0.f, a2 = 0.f, a3 = 0.f;
#pragma unroll
  for (int r = 0; r < DEG_E; ++r) {
    int idx = __shfl(my, r);
    ushort4 v = *(const ushort4*)(X3 + (size_t)idx * DF + lane * 4);
    a0 += b2f(v.x); a1 += b2f(v.y); a2 += b2f(v.z); a3 += b2f(v.w);
  }
  const float s = 1.f / DEG_E;
  ushort4 o;
  o.x = f2b(fmaxf(a0 * s, 0.f)); o.y = f2b(fmaxf(a1 * s, 0.f));
  o.z = f2b(fmaxf(a2 * s, 0.f)); o.w = f2b(fmaxf(a3 * s, 0.f));
  *(ushort4*)(E2 + (size_t)gw * HIDN + lane * 4) = o;
}

// layer2 E2N: mean of 8 gathered E2 rows -> X3[:, 256:512]
__global__ __launch_bounds__(256) void k_e2n2(const u16* __restrict__ E2, const int* __restrict__ emap,
                                              u16* __restrict__ X3) {
  int gw = (blockIdx.x * 256 + threadIdx.x) >> 6;
  int lane = threadIdx.x & 63;
  int my = (lane < DEG_N) ? emap[gw * DEG_N + lane] : 0;
  float a0 = 0.f, a1 = 0.f, a2 = 0.f, a3 = 0.f;
#pragma unroll
  for (int r = 0; r < DEG_N; ++r) {
    int idx = __shfl(my, r);
    ushort4 v = *(const ushort4*)(E2 + (size_t)idx * HIDN + lane * 4);
    a0 += b2f(v.x); a1 += b2f(v.y); a2 += b2f(v.z); a3 += b2f(v.w);
  }
  const float s = 1.f / DEG_N;
  ushort4 o;
  o.x = f2b(fmaxf(a0 * s, 0.f)); o.y = f2b(fmaxf(a1 * s, 0.f));
  o.z = f2b(fmaxf(a2 * s, 0.f)); o.w = f2b(fmaxf(a3 * s, 0.f));
  *(ushort4*)(X3 + (size_t)gw * DF + 2 * D0 + lane * 4) = o;
}

// ---- GEMM1: X3(100096x512) @ W1(512x256) + b1, relu -> H bf16 -----------
// A row-major KxDF; B = W1T N-major (256x512); 128x128 tile, BK=64, 4 waves.
__global__ __launch_bounds__(256) void k_gemm1(const u16* __restrict__ A, const u16* __restrict__ B,
                                               const float* __restrict__ bias, u16* __restrict__ C) {
  __shared__ u16 As[128 * 64];
  __shared__ u16 Bs[128 * 64];
  const int tid = threadIdx.x;
  const int lane = tid & 63;
  const int wid = tid >> 6;
  const int wr = wid >> 1, wc = wid & 1;
  const int m0 = blockIdx.x * 128;
  const int n0 = blockIdx.y * 128;
  const int srow = tid >> 3, sch = tid & 7;

  f32x4 acc[4][4] = {};

  for (int k0 = 0; k0 < DF; k0 += 64) {
    __syncthreads();
#pragma unroll
    for (int p = 0; p < 4; ++p) {
      int row = p * 32 + srow;
      int kb = (sch * 16) ^ ((row & 7) << 4);
      load_lds16(A + (size_t)(m0 + row) * DF + k0 + (kb >> 1), (char*)As + (p * 256 + tid) * 16);
    }
#pragma unroll
    for (int p = 0; p < 4; ++p) {
      int row = p * 32 + srow;
      int kb = (sch * 16) ^ ((row & 7) << 4);
      load_lds16(B + (size_t)(n0 + row) * DF + k0 + (kb >> 1), (char*)Bs + (p * 256 + tid) * 16);
    }
    __syncthreads();  // compiler drains vmcnt before s_barrier
#pragma unroll
    for (int kk = 0; kk < 2; ++kk) {
      bf16x8 a[4], b[4];
#pragma unroll
      for (int m = 0; m < 4; ++m) {
        int row = wr * 64 + m * 16 + (lane & 15);
        int kb = (kk * 64 + ((lane >> 4) * 16)) ^ ((row & 7) << 4);
        a[m] = *(const bf16x8*)((const char*)As + row * 128 + kb);
      }
#pragma unroll
      for (int n = 0; n < 4; ++n) {
        int row = wc * 64 + n * 16 + (lane & 15);
        int kb = (kk * 64 + ((lane >> 4) * 16)) ^ ((row & 7) << 4);
        b[n] = *(const bf16x8*)((const char*)Bs + row * 128 + kb);
      }
#pragma unroll
      for (int m = 0; m < 4; ++m)
#pragma unroll
        for (int n = 0; n < 4; ++n)
          acc[m][n] = __builtin_amdgcn_mfma_f32_16x16x32_bf16(a[m], b[n], acc[m][n], 0, 0, 0);
    }
  }

  const int rb = (lane >> 4) * 4;
  const int cb = lane & 15;
#pragma unroll
  for (int m = 0; m < 4; ++m) {
    int rbase = m0 + wr * 64 + m * 16 + rb;
#pragma unroll
    for (int n = 0; n < 4; ++n) {
      int c = n0 + wc * 64 + n * 16 + cb;
      float bv = bias[c];
#pragma unroll
      for (int v = 0; v < 4; ++v) {
        float x = acc[m][n][v] + bv;
        C[(size_t)(rbase + v) * HIDN + c] = f2b(fmaxf(x, 0.f));
      }
    }
  }
}

// ---- GEMM2: H(100096x256) @ W2(256x40) + b2 -> logits f32 ---------------
// 64-row tile, full K staged, N padded to 48 (3 frags), 4 waves x 16 rows.
__global__ __launch_bounds__(256) void k_gemm2(const u16* __restrict__ H, const u16* __restrict__ BT,
                                               const float* __restrict__ bias, float* __restrict__ LG) {
  __shared__ u16 As[64 * 256];
  __shared__ u16 Bs[48 * 256];
  const int tid = threadIdx.x;
  const int lane = tid & 63;
  const int w = tid >> 6;
  const size_t m0 = (size_t)blockIdx.x * 64;
  const int srow = tid >> 5, sch = tid & 31;
#pragma unroll
  for (int p = 0; p < 8; ++p) {
    int row = p * 8 + srow;
    int kb = (sch * 16) ^ ((row & 7) << 4);
    load_lds16(H + (m0 + row) * HIDN + (kb >> 1), (char*)As + (p * 256 + tid) * 16);
  }
#pragma unroll
  for (int p = 0; p < 6; ++p) {
    int row = p * 8 + srow;
    int kb = (sch * 16) ^ ((row & 7) << 4);
    load_lds16(BT + (size_t)row * HIDN + (kb >> 1), (char*)Bs + (p * 256 + tid) * 16);
  }
  __syncthreads();
  f32x4 acc[3] = {};
  const int r0 = w * 16;
#pragma unroll
  for (int kk = 0; kk < 8; ++kk) {
    int arow = r0 + (lane & 15);
    int kb = (kk * 64 + ((lane >> 4) * 16)) ^ ((arow & 7) << 4);
    bf16x8 a = *(const bf16x8*)((const char*)As + arow * 512 + kb);
#pragma unroll
    for (int n = 0; n < 3; ++n) {
      int brow = n * 16 + (lane & 15);
      int kb2 = (kk * 64 + ((lane >> 4) * 16)) ^ ((brow & 7) << 4);
      bf16x8 b = *(const bf16x8*)((const char*)Bs + brow * 512 + kb2);
      acc[n] = __builtin_amdgcn_mfma_f32_16x16x32_bf16(a, b, acc[n], 0, 0, 0);
    }
  }
  const int rb = (lane >> 4) * 4, cb = lane & 15;
#pragma unroll
  for (int n = 0; n < 3; ++n) {
    int c = n * 16 + cb;
    if (c < NC) {
      float bv = bias[c];
#pragma unroll
      for (int v = 0; v < 4; ++v) {
        size_t r = m0 + r0 + rb + v;
        LG[r * NC + c] = acc[n][v] + bv;
      }
    }
  }
}

// ---- log_softmax: thread per row ----------------------------------------
__global__ __launch_bounds__(256) void k_lsm(const float* __restrict__ LG, float* __restrict__ out) {
  int i = blockIdx.x * 256 + threadIdx.x;
  if (i >= N_NODES) return;
  const float* z = LG + (size_t)i * NC;
  float zz[NC];
  float m = -1e30f;
#pragma unroll
  for (int c = 0; c < NC; ++c) { zz[c] = z[c]; m = fmaxf(m, zz[c]); }
  float s = 0.f;
#pragma unroll
  for (int c = 0; c < NC; ++c) { zz[c] -= m; s += expf(zz[c]); }
  float lse = logf(s);
  float* o = out + (size_t)i * NC;
#pragma unroll
  for (int c = 0; c < NC; ++c) o[c] = zz[c] - lse;
}

// ---- launch -------------------------------------------------------------

extern "C" void kernel_launch(void* const* d_in, const int* in_sizes, int n_in,
                              void* d_out, int out_size, void* d_ws, size_t ws_size,
                              hipStream_t stream) {
  const float* node_x    = (const float*)d_in[0];
  const int*   nodes_map = (const int*)d_in[1];
  const int*   edges_map = (const int*)d_in[3];
  const float* W1        = (const float*)d_in[5];
  const float* b1        = (const float*)d_in[6];
  const float* W2        = (const float*)d_in[7];
  const float* b2        = (const float*)d_in[8];
  float* out = (float*)d_out;
  char* ws = (char*)d_ws;

  // ws layout (bytes, 256-aligned)
  u16*   X3  = (u16*)(ws + 0);                      // 100096*512*2 = 102,498,304
  u16*   E1  = (u16*)(ws + 102498304);              // 50000*128*2  =  12,800,000
  u16*   E2  = (u16*)(ws + 115298304);              // 50000*256*2  =  25,600,000
  u16*   H   = (u16*)(ws + 140898304);              // 100096*256*2 =  51,249,152
  u16*   W1T = (u16*)(ws + 192147456);              // 256*512*2    =     262,144
  u16*   W2T = (u16*)(ws + 192409600);              // 48*256*2     =      24,576
  float* LG  = (float*)(ws + 192434176);            // 100096*40*4  =  16,015,360

  k_node_to_x3<<<12500, 256, 0, stream>>>(node_x, X3);
  k_zero_pad<<<48, 256, 0, stream>>>(X3);
  k_w1t<<<512, 256, 0, stream>>>(W1, W1T);
  k_w2t<<<48, 256, 0, stream>>>(W2, W2T);

  // layer 1
  k_n2e1<<<N_EDGES / 4, 256, 0, stream>>>(X3, nodes_map, E1);
  k_e2n1<<<N_NODES / 4, 256, 0, stream>>>(E1, edges_map, X3);
  // layer 2
  k_n2e2<<<N_EDGES / 4, 256, 0, stream>>>(X3, nodes_map, E2);
  k_e2n2<<<N_NODES / 4, 256, 0, stream>>>(E2, edges_map, X3);

  // head
  dim3 g1(MPAD / 128, 2);
  k_gemm1<<<g1, 256, 0, stream>>>(X3, W1T, b1, H);
  k_gemm2<<<MPAD / 64, 256, 0, stream>>>(H, W2T, b2, LG);
  k_lsm<<<(N_NODES + 255) / 256, 256, 0, stream>>>(LG, out);
}

// Round 2
// 272.557 us; speedup vs baseline: 1.3365x; 1.3365x over previous
//
#include <hip/hip_runtime.h>
#include <hip/hip_bf16.h>

typedef unsigned int u32;
typedef unsigned short u16;
typedef __attribute__((ext_vector_type(4))) float f32x4;
typedef __attribute__((ext_vector_type(8))) short bf16x8;

#define N_NODES 100000
#define N_EDGES 50000
#define D0      128
#define MPAD    100096
#define DF2     384
#define HIDN    256
#define NC      40

__device__ __forceinline__ float b2f(u32 h) { return __uint_as_float(h << 16); }
__device__ __forceinline__ u16 f2b(float f) {
  u32 u = __float_as_uint(f);
  u32 r = (u + 0x7fffu + ((u >> 16) & 1u)) >> 16;
  return (u16)r;
}
__device__ __forceinline__ void load_lds16(const void* g, void* l) {
  __builtin_amdgcn_global_load_lds((const __attribute__((address_space(1))) u32*)g,
                                   (__attribute__((address_space(3))) u32*)l, 16, 0, 0);
}

// ---- prep ---------------------------------------------------------------

// node_x f32 (100000x128) -> x0b bf16 compact (stride 128)
__global__ __launch_bounds__(256) void k_node_to_x0(const float* __restrict__ x, u16* __restrict__ x0b) {
  int t = blockIdx.x * 256 + threadIdx.x;           // 3.2M threads, 4 elems each
  int e4 = t * 4;
  const float4 v = *(const float4*)(x + e4);
  ushort4 o;
  o.x = f2b(v.x); o.y = f2b(v.y); o.z = f2b(v.z); o.w = f2b(v.w);
  *(ushort4*)(x0b + e4) = o;
}

// zero pad rows 100000..100095 of x0b, nx1, nx2b
__global__ __launch_bounds__(256) void k_pad(u16* __restrict__ x0b, u16* __restrict__ nx1,
                                             u16* __restrict__ nx2b) {
  int t4 = (blockIdx.x * 256 + threadIdx.x) * 4;    // 36 blocks: 3*12288 elems
  const size_t PO = (size_t)N_NODES * D0;
  ushort4 z; z.x = z.y = z.z = z.w = 0;
  u16* dst;
  if (t4 < 12288)      dst = x0b  + PO + t4;
  else if (t4 < 24576) dst = nx1  + PO + t4 - 12288;
  else                 dst = nx2b + PO + t4 - 24576;
  *(ushort4*)dst = z;
}

// W1 (512x256 f32 K-major) -> W1T (256x384 bf16 N-major) with rows 128:256 + 256:384 folded
__global__ __launch_bounds__(256) void k_w1t_fold(const float* __restrict__ W1, u16* __restrict__ W1T) {
  int n = blockIdx.x;                               // 256 blocks
  for (int k = threadIdx.x; k < DF2; k += 256) {
    float v;
    if (k < 128)      v = W1[k * 256 + n];
    else if (k < 256) v = W1[k * 256 + n] + W1[(k + 128) * 256 + n];
    else              v = W1[(k + 128) * 256 + n];
    W1T[(size_t)n * DF2 + k] = f2b(v);
  }
}

// W2 (256x40 f32) -> W2T (48x256 bf16 N-major, rows 40..47 zero)
__global__ __launch_bounds__(256) void k_w2t(const float* __restrict__ W2, u16* __restrict__ W2T) {
  int t = blockIdx.x * 256 + threadIdx.x;           // 48*256
  int n = t >> 8, k = t & 255;
  W2T[t] = (n < NC) ? f2b(W2[k * NC + n]) : (u16)0;
}

// ---- gather / segment-mean (wave per segment, 128-col compact) ----------

template<int DEG>
__global__ __launch_bounds__(256) void k_gather(const u16* __restrict__ src,
                                                const int* __restrict__ map,
                                                u16* __restrict__ dst) {
  int gw = (blockIdx.x * 256 + threadIdx.x) >> 6;   // segment id
  int lane = threadIdx.x & 63;
  int my = (lane < DEG) ? map[gw * DEG + lane] : 0;
  float a0 = 0.f, a1 = 0.f;
#pragma unroll
  for (int r = 0; r < DEG; ++r) {
    int idx = __shfl(my, r);
    u32 v = *(const u32*)(src + (size_t)idx * D0 + lane * 2);
    a0 += b2f(v & 0xffffu); a1 += b2f(v >> 16);
  }
  const float s = 1.f / DEG;
  u32 o = (u32)f2b(fmaxf(a0 * s, 0.f)) | ((u32)f2b(fmaxf(a1 * s, 0.f)) << 16);
  *(u32*)(dst + (size_t)gw * D0 + lane * 2) = o;
}

// ---- fused head: [x0|nx1|nx2b](100096x384) @ W1T -> relu -> @W2 -> lsm --
// BM=64, BN=256 (full), 4 waves (1x4), BK=64, 6 K-steps.
__global__ __launch_bounds__(256) void k_head(const u16* __restrict__ x0b,
                                              const u16* __restrict__ nx1,
                                              const u16* __restrict__ nx2b,
                                              const u16* __restrict__ W1T,
                                              const float* __restrict__ b1,
                                              const u16* __restrict__ W2T,
                                              const float* __restrict__ b2,
                                              float* __restrict__ out) {
  __shared__ char lds[40960];
  u16* As = (u16*)lds;                              // 64x64 bf16 = 8KB
  u16* Bs = (u16*)(lds + 8192);                     // 256x64 bf16 = 32KB
  u16* Hs = (u16*)lds;                              // 64x256 bf16 = 32KB (reuse after main loop)
  const int tid = threadIdx.x;
  const int lane = tid & 63;
  const int wid = tid >> 6;                         // wave = column block wc
  const int m0 = blockIdx.x * 64;
  const int srow = tid >> 3, sch = tid & 7;

  f32x4 acc[4][4] = {};

#pragma unroll
  for (int ks = 0; ks < 6; ++ks) {
    const int k0 = ks * 64;
    const u16* Ap = (ks < 2) ? x0b : (ks < 4) ? nx1 : nx2b;
    const int klocal = (ks & 1) * 64;
    __syncthreads();
#pragma unroll
    for (int p = 0; p < 2; ++p) {                   // A: 64 rows x 128B
      int row = p * 32 + srow;
      int kb = (sch * 16) ^ ((row & 7) << 4);
      load_lds16(Ap + (size_t)(m0 + row) * D0 + klocal + (kb >> 1),
                 (char*)As + (p * 256 + tid) * 16);
    }
#pragma unroll
    for (int p = 0; p < 8; ++p) {                   // B: 256 rows x 128B
      int row = p * 32 + srow;
      int kb = (sch * 16) ^ ((row & 7) << 4);
      load_lds16(W1T + (size_t)row * DF2 + k0 + (kb >> 1),
                 (char*)Bs + (p * 256 + tid) * 16);
    }
    __syncthreads();                                // compiler drains vmcnt before barrier
#pragma unroll
    for (int kk = 0; kk < 2; ++kk) {
      bf16x8 a[4], b[4];
#pragma unroll
      for (int m = 0; m < 4; ++m) {
        int row = m * 16 + (lane & 15);
        int kb = (kk * 64 + ((lane >> 4) * 16)) ^ ((row & 7) << 4);
        a[m] = *(const bf16x8*)((const char*)As + row * 128 + kb);
      }
#pragma unroll
      for (int n = 0; n < 4; ++n) {
        int row = wid * 64 + n * 16 + (lane & 15);
        int kb = (kk * 64 + ((lane >> 4) * 16)) ^ ((row & 7) << 4);
        b[n] = *(const bf16x8*)((const char*)Bs + row * 128 + kb);
      }
#pragma unroll
      for (int m = 0; m < 4; ++m)
#pragma unroll
        for (int n = 0; n < 4; ++n)
          acc[m][n] = __builtin_amdgcn_mfma_f32_16x16x32_bf16(a[m], b[n], acc[m][n], 0, 0, 0);
    }
  }

  __syncthreads();                                  // As/Bs dead; reuse as Hs
  const int rb = (lane >> 4) * 4, cb = lane & 15;
#pragma unroll
  for (int n = 0; n < 4; ++n) {                     // H = relu(acc + b1) -> Hs (swizzled)
    int c = wid * 64 + n * 16 + cb;
    float bv = b1[c];
#pragma unroll
    for (int m = 0; m < 4; ++m) {
#pragma unroll
      for (int v = 0; v < 4; ++v) {
        int r = m * 16 + rb + v;
        u32 byo = ((u32)(r << 9) + (u32)(c << 1)) ^ (u32)((r & 7) << 4);
        *(u16*)((char*)Hs + byo) = f2b(fmaxf(acc[m][n][v] + bv, 0.f));
      }
    }
  }
  __syncthreads();

  // GEMM2: each wave owns 16 rows; K=256; N=48 (3 frags); W2 frags from L2-hot global
  f32x4 acc2[3] = {};
  const int r0g = wid * 16;
#pragma unroll
  for (int kk = 0; kk < 8; ++kk) {
    int arow = r0g + (lane & 15);
    int kb = (kk * 64 + ((lane >> 4) * 16)) ^ ((arow & 7) << 4);
    bf16x8 a = *(const bf16x8*)((const char*)Hs + arow * 512 + kb);
#pragma unroll
    for (int n = 0; n < 3; ++n) {
      int brow = n * 16 + (lane & 15);
      bf16x8 b = *(const bf16x8*)(W2T + brow * 256 + kk * 32 + (lane >> 4) * 8);
      acc2[n] = __builtin_amdgcn_mfma_f32_16x16x32_bf16(a, b, acc2[n], 0, 0, 0);
    }
  }

  // log-softmax over 40 cols; rows r0g + rb + v; reduce across the 16-lane col group
  float bias[3];
#pragma unroll
  for (int n = 0; n < 3; ++n) {
    int c = n * 16 + cb;
    bias[n] = (c < NC) ? b2[c] : 0.f;
  }
#pragma unroll
  for (int v = 0; v < 4; ++v) {
    float z[3];
    float mx = -1e30f;
#pragma unroll
    for (int n = 0; n < 3; ++n) {
      int c = n * 16 + cb;
      z[n] = (c < NC) ? (acc2[n][v] + bias[n]) : -1e30f;
      mx = fmaxf(mx, z[n]);
    }
#pragma unroll
    for (int o = 1; o < 16; o <<= 1) mx = fmaxf(mx, __shfl_xor(mx, o));
    float s = 0.f;
#pragma unroll
    for (int n = 0; n < 3; ++n) {
      int c = n * 16 + cb;
      if (c < NC) s += expf(z[n] - mx);
    }
#pragma unroll
    for (int o = 1; o < 16; o <<= 1) s += __shfl_xor(s, o);
    float lse = logf(s);
    int grow = m0 + r0g + rb + v;
    if (grow < N_NODES) {
#pragma unroll
      for (int n = 0; n < 3; ++n) {
        int c = n * 16 + cb;
        if (c < NC) out[(size_t)grow * NC + c] = z[n] - mx - lse;
      }
    }
  }
}

// ---- launch -------------------------------------------------------------

extern "C" void kernel_launch(void* const* d_in, const int* in_sizes, int n_in,
                              void* d_out, int out_size, void* d_ws, size_t ws_size,
                              hipStream_t stream) {
  const float* node_x    = (const float*)d_in[0];
  const int*   nodes_map = (const int*)d_in[1];
  const int*   edges_map = (const int*)d_in[3];
  const float* W1        = (const float*)d_in[5];
  const float* b1        = (const float*)d_in[6];
  const float* W2        = (const float*)d_in[7];
  const float* b2        = (const float*)d_in[8];
  float* out = (float*)d_out;
  char* ws = (char*)d_ws;

  // ws layout (bytes, 16B-aligned)
  u16* x0b  = (u16*)(ws + 0);                       // 100096*128*2 = 25,624,576
  u16* nx1  = (u16*)(ws + 25624576);                // 25,624,576
  u16* nx2b = (u16*)(ws + 51249152);                // 25,624,576
  u16* E1   = (u16*)(ws + 76873728);                // 50000*128*2 = 12,800,000
  u16* E2b  = (u16*)(ws + 89673728);                // 12,800,000
  u16* W1T  = (u16*)(ws + 102473728);               // 256*384*2 = 196,608
  u16* W2T  = (u16*)(ws + 102670336);               // 48*256*2  =  24,576

  k_node_to_x0<<<12500, 256, 0, stream>>>(node_x, x0b);
  k_pad<<<36, 256, 0, stream>>>(x0b, nx1, nx2b);
  k_w1t_fold<<<256, 256, 0, stream>>>(W1, W1T);
  k_w2t<<<48, 256, 0, stream>>>(W2, W2T);

  // layer 1
  k_gather<16><<<N_EDGES / 4, 256, 0, stream>>>(x0b, nodes_map, E1);   // E1 = relu(mean x0)
  k_gather<8><<<N_NODES / 4, 256, 0, stream>>>(E1, edges_map, nx1);    // nx1 = relu(mean E1)
  // layer 2 (dedup: only the new halves)
  k_gather<16><<<N_EDGES / 4, 256, 0, stream>>>(nx1, nodes_map, E2b);  // E2b = relu(mean nx1)
  k_gather<8><<<N_NODES / 4, 256, 0, stream>>>(E2b, edges_map, nx2b);  // nx2b = relu(mean E2b)

  // fused head: GEMM1(+fold) -> relu -> GEMM2 -> log_softmax
  k_head<<<MPAD / 64, 256, 0, stream>>>(x0b, nx1, nx2b, W1T, b1, W2T, b2, out);
}

// Round 3
// 218.691 us; speedup vs baseline: 1.6657x; 1.2463x over previous
//
#include <hip/hip_runtime.h>
#include <hip/hip_bf16.h>

typedef unsigned int u32;
typedef unsigned short u16;
typedef unsigned char u8;
typedef __attribute__((ext_vector_type(4))) float f32x4;
typedef __attribute__((ext_vector_type(2))) float f32x2;

#define N_NODES 100000
#define N_EDGES 50000
#define D0      128
#define MPAD    100096
#define HIDN    256
#define NC      40

__device__ __forceinline__ float b2f(u32 h) { return __uint_as_float(h << 16); }
__device__ __forceinline__ u16 f2b(float f) {
  u32 u = __float_as_uint(f);
  u32 r = (u + 0x7fffu + ((u >> 16) & 1u)) >> 16;
  return (u16)r;
}
__device__ __forceinline__ void load_lds16(const void* g, void* l) {
  __builtin_amdgcn_global_load_lds((const __attribute__((address_space(1))) u32*)g,
                                   (__attribute__((address_space(3))) u32*)l, 16, 0, 0);
}

// ---- prep ---------------------------------------------------------------

// node_x f32 (100000x128) -> x0f fp8 e4m3 compact (stride 128)
__global__ __launch_bounds__(256) void k_node_to_x0f(const float* __restrict__ x, u8* __restrict__ x0f) {
  int t = blockIdx.x * 256 + threadIdx.x;           // 3.2M threads, 4 elems each
  const float4 v = *(const float4*)(x + (size_t)t * 4);
  int w = __builtin_amdgcn_cvt_pk_fp8_f32(v.x, v.y, 0, false);
  w = __builtin_amdgcn_cvt_pk_fp8_f32(v.z, v.w, w, true);
  *(u32*)(x0f + (size_t)t * 4) = (u32)w;
}

// zero pad rows 100000..100095 of x0f, nx1f, nx2f (96*128B = 3072 u32 each)
__global__ __launch_bounds__(256) void k_padf(u8* __restrict__ x0f, u8* __restrict__ nx1f,
                                              u8* __restrict__ nx2f) {
  int t = blockIdx.x * 256 + threadIdx.x;           // 36 blocks -> 9216
  const size_t PO = (size_t)N_NODES * D0;
  u32* dst;
  if (t < 3072)      dst = (u32*)(x0f + PO) + t;
  else if (t < 6144) dst = (u32*)(nx1f + PO) + (t - 3072);
  else               dst = (u32*)(nx2f + PO) + (t - 6144);
  *dst = 0;
}

// W1 (512x256 f32 K-major) -> W1F (256x384 fp8 N-major, x64 scale), middle halves folded
__global__ __launch_bounds__(192) void k_w1ff(const float* __restrict__ W1, u8* __restrict__ W1F) {
  int n = blockIdx.x;                               // 256 blocks
  int t = threadIdx.x;                              // 192: k pair (2t, 2t+1)
  float v[2];
#pragma unroll
  for (int j = 0; j < 2; ++j) {
    int k = 2 * t + j;
    if (k < 128)      v[j] = W1[k * 256 + n];
    else if (k < 256) v[j] = W1[k * 256 + n] + W1[(k + 128) * 256 + n];
    else              v[j] = W1[(k + 128) * 256 + n];
  }
  int w = __builtin_amdgcn_cvt_pk_fp8_f32(v[0] * 64.f, v[1] * 64.f, 0, false);
  *(u16*)(W1F + (size_t)n * 384 + 2 * t) = (u16)w;
}

// W2 (256x40 f32) -> W2T (48x256 bf16 N-major, rows 40..47 zero)
__global__ __launch_bounds__(256) void k_w2t(const float* __restrict__ W2, u16* __restrict__ W2T) {
  int t = blockIdx.x * 256 + threadIdx.x;           // 48*256
  int n = t >> 8, k = t & 255;
  W2T[t] = (n < NC) ? f2b(W2[k * NC + n]) : (u16)0;
}

// ---- gather / segment-mean (wave per segment, 128B fp8 rows) ------------

template<int DEG>
__global__ __launch_bounds__(256) void k_gatherf(const u8* __restrict__ src,
                                                 const int* __restrict__ map,
                                                 u8* __restrict__ dst) {
  int gw = (blockIdx.x * 256 + threadIdx.x) >> 6;   // segment id
  int lane = threadIdx.x & 63;
  int my = (lane < DEG) ? map[gw * DEG + lane] : 0;
  float a0 = 0.f, a1 = 0.f;
#pragma unroll
  for (int r = 0; r < DEG; ++r) {
    int idx = __shfl(my, r);
    u16 h = *(const u16*)(src + (size_t)idx * D0 + lane * 2);
    f32x2 v = __builtin_amdgcn_cvt_pk_f32_fp8((int)h, false);
    a0 += v[0]; a1 += v[1];
  }
  const float s = 1.f / DEG;
  int w = __builtin_amdgcn_cvt_pk_fp8_f32(fmaxf(a0 * s, 0.f), fmaxf(a1 * s, 0.f), 0, false);
  *(u16*)(dst + (size_t)gw * D0 + lane * 2) = (u16)w;
}

// ---- fused head: [x0|nx1|nx2](100096x384 fp8) @ W1F -> relu -> @W2 -> lsm
// BM=64, BN=256 (full), 4 waves, BK=128 (one source buffer per K-step).
__global__ __launch_bounds__(256) void k_head(const u8* __restrict__ x0f,
                                              const u8* __restrict__ nx1f,
                                              const u8* __restrict__ nx2f,
                                              const u8* __restrict__ W1F,
                                              const float* __restrict__ b1,
                                              const u16* __restrict__ W2T,
                                              const float* __restrict__ b2,
                                              float* __restrict__ out) {
  __shared__ char lds[40960];
  u8*  As = (u8*)lds;                               // 64 x 128B = 8KB
  u8*  Bs = (u8*)(lds + 8192);                      // 256 x 128B = 32KB
  u16* Hs = (u16*)lds;                              // 64x256 bf16 = 32KB (reuse)
  const int tid = threadIdx.x;
  const int lane = tid & 63;
  const int wid = tid >> 6;                         // wave = column block
  const int m0 = blockIdx.x * 64;

  f32x4 acc[4][4] = {};

#pragma unroll
  for (int ks = 0; ks < 3; ++ks) {
    const u8* Ap = (ks == 0) ? x0f : (ks == 1) ? nx1f : nx2f;
    __syncthreads();
    const int c = tid & 7;
#pragma unroll
    for (int p = 0; p < 2; ++p) {                   // A: 64 rows x 128B
      int row = p * 32 + (tid >> 3);
      load_lds16(Ap + (size_t)(m0 + row) * D0 + ((c ^ (row & 7)) << 4),
                 (char*)As + (p * 256 + tid) * 16);
    }
#pragma unroll
    for (int p = 0; p < 8; ++p) {                   // B: 256 rows x 128B
      int row = p * 32 + (tid >> 3);
      load_lds16(W1F + (size_t)row * 384 + ks * 128 + ((c ^ (row & 7)) << 4),
                 (char*)Bs + (p * 256 + tid) * 16);
    }
    __syncthreads();                                // drains vmcnt before barrier
#pragma unroll
    for (int kk = 0; kk < 4; ++kk) {
      long av[4], bv[4];
#pragma unroll
      for (int m = 0; m < 4; ++m) {
        int r = m * 16 + (lane & 15);
        int byo = (kk * 32 + ((lane >> 4) * 8)) ^ ((r & 7) << 4);
        av[m] = *(const long*)(As + r * 128 + byo);
      }
#pragma unroll
      for (int n = 0; n < 4; ++n) {
        int r = wid * 64 + n * 16 + (lane & 15);
        int byo = (kk * 32 + ((lane >> 4) * 8)) ^ ((r & 7) << 4);
        bv[n] = *(const long*)(Bs + r * 128 + byo);
      }
#pragma unroll
      for (int m = 0; m < 4; ++m)
#pragma unroll
        for (int n = 0; n < 4; ++n)
          acc[m][n] = __builtin_amdgcn_mfma_f32_16x16x32_fp8_fp8(av[m], bv[n], acc[m][n], 0, 0, 0);
    }
  }

  __syncthreads();                                  // As/Bs dead; reuse as Hs
  const int rb = (lane >> 4) * 4, cb = lane & 15;
#pragma unroll
  for (int n = 0; n < 4; ++n) {                     // H = relu(acc/64 + b1) -> Hs (swizzled)
    int col = wid * 64 + n * 16 + cb;
    float bv = b1[col];
#pragma unroll
    for (int m = 0; m < 4; ++m) {
#pragma unroll
      for (int v = 0; v < 4; ++v) {
        int r = m * 16 + rb + v;
        u32 byo = ((u32)(r << 9) + (u32)(col << 1)) ^ (u32)((r & 7) << 4);
        *(u16*)((char*)Hs + byo) = f2b(fmaxf(acc[m][n][v] * 0.015625f + bv, 0.f));
      }
    }
  }
  __syncthreads();

  // GEMM2: each wave owns 16 rows; K=256; N=48 (3 frags); W2 frags from L2-hot global
  typedef __attribute__((ext_vector_type(8))) short bf16x8;
  f32x4 acc2[3] = {};
  const int r0g = wid * 16;
#pragma unroll
  for (int kk = 0; kk < 8; ++kk) {
    int arow = r0g + (lane & 15);
    int kb = (kk * 64 + ((lane >> 4) * 16)) ^ ((arow & 7) << 4);
    bf16x8 a = *(const bf16x8*)((const char*)Hs + arow * 512 + kb);
#pragma unroll
    for (int n = 0; n < 3; ++n) {
      int brow = n * 16 + (lane & 15);
      bf16x8 b = *(const bf16x8*)(W2T + brow * 256 + kk * 32 + (lane >> 4) * 8);
      acc2[n] = __builtin_amdgcn_mfma_f32_16x16x32_bf16(a, b, acc2[n], 0, 0, 0);
    }
  }

  // log-softmax over 40 cols; reduce across the 16-lane col group
  float bias[3];
#pragma unroll
  for (int n = 0; n < 3; ++n) {
    int c2 = n * 16 + cb;
    bias[n] = (c2 < NC) ? b2[c2] : 0.f;
  }
#pragma unroll
  for (int v = 0; v < 4; ++v) {
    float z[3];
    float mx = -1e30f;
#pragma unroll
    for (int n = 0; n < 3; ++n) {
      int c2 = n * 16 + cb;
      z[n] = (c2 < NC) ? (acc2[n][v] + bias[n]) : -1e30f;
      mx = fmaxf(mx, z[n]);
    }
#pragma unroll
    for (int o = 1; o < 16; o <<= 1) mx = fmaxf(mx, __shfl_xor(mx, o));
    float s = 0.f;
#pragma unroll
    for (int n = 0; n < 3; ++n) {
      int c2 = n * 16 + cb;
      if (c2 < NC) s += expf(z[n] - mx);
    }
#pragma unroll
    for (int o = 1; o < 16; o <<= 1) s += __shfl_xor(s, o);
    float lse = logf(s);
    int grow = m0 + r0g + rb + v;
    if (grow < N_NODES) {
#pragma unroll
      for (int n = 0; n < 3; ++n) {
        int c2 = n * 16 + cb;
        if (c2 < NC) out[(size_t)grow * NC + c2] = z[n] - mx - lse;
      }
    }
  }
}

// ---- launch -------------------------------------------------------------

extern "C" void kernel_launch(void* const* d_in, const int* in_sizes, int n_in,
                              void* d_out, int out_size, void* d_ws, size_t ws_size,
                              hipStream_t stream) {
  const float* node_x    = (const float*)d_in[0];
  const int*   nodes_map = (const int*)d_in[1];
  const int*   edges_map = (const int*)d_in[3];
  const float* W1        = (const float*)d_in[5];
  const float* b1        = (const float*)d_in[6];
  const float* W2        = (const float*)d_in[7];
  const float* b2        = (const float*)d_in[8];
  float* out = (float*)d_out;
  char* ws = (char*)d_ws;

  // ws layout (bytes, 16B-aligned)
  u8*  x0f  = (u8*)(ws + 0);                        // 100096*128 = 12,812,288
  u8*  nx1f = (u8*)(ws + 12812288);                 // 12,812,288
  u8*  nx2f = (u8*)(ws + 25624576);                 // 12,812,288
  u8*  E1f  = (u8*)(ws + 38436864);                 // 50000*128 = 6,400,000
  u8*  E2f  = (u8*)(ws + 44836864);                 // 6,400,000
  u8*  W1F  = (u8*)(ws + 51236864);                 // 256*384   =    98,304
  u16* W2T  = (u16*)(ws + 51335168);                // 48*256*2  =    24,576

  k_node_to_x0f<<<12500, 256, 0, stream>>>(node_x, x0f);
  k_padf<<<36, 256, 0, stream>>>(x0f, nx1f, nx2f);
  k_w1ff<<<256, 192, 0, stream>>>(W1, W1F);
  k_w2t<<<48, 256, 0, stream>>>(W2, W2T);

  // layer 1
  k_gatherf<16><<<N_EDGES / 4, 256, 0, stream>>>(x0f, nodes_map, E1f);   // E1 = relu(mean x0)
  k_gatherf<8><<<N_NODES / 4, 256, 0, stream>>>(E1f, edges_map, nx1f);   // nx1 = relu(mean E1)
  // layer 2 (dedup: only the new halves)
  k_gatherf<16><<<N_EDGES / 4, 256, 0, stream>>>(nx1f, nodes_map, E2f);  // E2 = relu(mean nx1)
  k_gatherf<8><<<N_NODES / 4, 256, 0, stream>>>(E2f, edges_map, nx2f);   // nx2 = relu(mean E2)

  // fused head: GEMM1(fp8, folded W) -> relu -> GEMM2(bf16) -> log_softmax
  k_head<<<MPAD / 64, 256, 0, stream>>>(x0f, nx1f, nx2f, W1F, b1, W2T, b2, out);
}